// Round 6
// baseline (1226.130 us; speedup 1.0000x reference)
//
#include <hip/hip_runtime.h>
#include <hip/hip_cooperative_groups.h>

namespace cg = cooperative_groups;

#define EPSF    1e-10f
#define MAXENT  6.93147180559945286f   // ln(1024)
#define SCALEF  0.37796447300922720f   // 1/sqrt(7)

// ---------------- helpers ----------------
__device__ __forceinline__ float wave_sum(float v) {
#pragma unroll
  for (int off = 32; off > 0; off >>= 1) v += __shfl_xor(v, off);
  return v;
}
__device__ __forceinline__ void wave_sum2(float& a, float& b) {
#pragma unroll
  for (int off = 32; off > 0; off >>= 1) {
    a += __shfl_xor(a, off);
    b += __shfl_xor(b, off);
  }
}
__device__ __forceinline__ void fma4(float a, float4 b, float4& c) {
  c.x = fmaf(a, b.x, c.x); c.y = fmaf(a, b.y, c.y);
  c.z = fmaf(a, b.z, c.z); c.w = fmaf(a, b.w, c.w);
}
__device__ __forceinline__ float dot4(float4 a, float4 b, float acc) {
  acc = fmaf(a.x, b.x, acc); acc = fmaf(a.y, b.y, acc);
  acc = fmaf(a.z, b.z, acc); acc = fmaf(a.w, b.w, acc);
  return acc;
}
__device__ __forceinline__ float4 exp4(float4 s) {
  return make_float4(__expf(s.x), __expf(s.y), __expf(s.z), __expf(s.w));
}
// C' = min(C / (C*v + eps), 1e37) componentwise — the Sinkhorn normalizer update
__device__ __forceinline__ float4 cupd(float4 c, float4 v) {
  c.x = fminf(c.x / fmaf(c.x, v.x, EPSF), 1e37f);
  c.y = fminf(c.y / fmaf(c.y, v.y, EPSF), 1e37f);
  c.z = fminf(c.z / fmaf(c.z, v.z, EPSF), 1e37f);
  c.w = fminf(c.w / fmaf(c.w, v.w, EPSF), 1e37f);
  return c;
}
// P0 = (E1*exp(s1) + E2*exp(s2) + EPS)^10, E_h = 0.5/L_h (no-max softmax; |s|<~12 so safe)
__device__ __forceinline__ float p0e(float s1, float s2, float E1, float E2) {
  float p = fmaf(E1, __expf(s1), fmaf(E2, __expf(s2), EPSF));
  float p2 = p * p, p4 = p2 * p2, p5 = p4 * p;
  return p5 * p5;
}

// ---------------- kernel 0: QKV projection (d-major, Q pre-scaled) + R/C/vW init ----------------
__global__ __launch_bounds__(256) void qkv_kernel(
    const float* __restrict__ x,
    const float* __restrict__ Wq, const float* __restrict__ bq,
    const float* __restrict__ Wk, const float* __restrict__ bk,
    const float* __restrict__ Wv, const float* __restrict__ bv,
    float* __restrict__ Qt, float* __restrict__ Kt, float* __restrict__ Vt,
    float* __restrict__ R, float* __restrict__ CA, float* __restrict__ CB,
    float* __restrict__ vW) {
  int row = blockIdx.x * 256 + threadIdx.x;     // 65536 rows
  int b = row >> 10, i = row & 1023;
  float xv[14];
#pragma unroll
  for (int k = 0; k < 14; k++) xv[k] = x[row * 14 + k];
#pragma unroll
  for (int d = 0; d < 14; d++) {
    float q = bq[d], kk = bk[d], vv = bv[d];
#pragma unroll
    for (int k = 0; k < 14; k++) {
      q  = fmaf(xv[k], Wq[d * 14 + k], q);
      kk = fmaf(xv[k], Wk[d * 14 + k], kk);
      vv = fmaf(xv[k], Wv[d * 14 + k], vv);
    }
    int o = b * 14336 + d * 1024 + i;
    Qt[o] = q * SCALEF;
    Kt[o] = kk; Vt[o] = vv;
  }
  R[row] = 1.0f;
  CA[row] = 1.0f;
  CB[row] = 1.0f;
  vW[row] = 0.f;
  vW[row + 65536] = 0.f;         // W1: iteration-1 accumulator
  vW[row + 131072] = 0.f;        // W2: iteration-2 accumulator
  vW[row + 196608] = 0.f;        // W3 (re-zeroed by p0 phase; harmless)
}

// ---------------- kernel 1: attention + entropy/certainty + E1/E2 + FUSED out-proj ----------------
// 256 thr = 4 waves x 2 rows = 8 rows/block, grid 8192. K and V read straight from
// global (L2-resident). (256,2): allocator needs ~120 VGPR; (256,4) forced 64 and
// spilled 684 MB scratch (round 1) — do not tighten.
__global__ __launch_bounds__(256, 2) void attn_kernel(
    const float* __restrict__ Qt, const float* __restrict__ Kt, const float* __restrict__ Vt,
    const float* __restrict__ cert_in,
    const float* __restrict__ WoG, const float* __restrict__ boG,
    float* __restrict__ E1o, float* __restrict__ E2o,
    float* __restrict__ out_, float* __restrict__ cert_out) {
  __shared__ float WoS[196];
  __shared__ float boS[14];
  int b = blockIdx.x >> 7;                      // 128 blocks per batch
  int rg = blockIdx.x & 127;                    // 8 rows per block
  int tid = threadIdx.x;
  if (tid < 196) WoS[tid] = WoG[tid];
  if (tid < 14) boS[tid] = boG[tid];
  __syncthreads();

  int wave = tid >> 6, lane = tid & 63;
  int i0 = rg * 8 + wave * 2;
  const float4* Ktb = (const float4*)(Kt + b * 14336);
  const float4* Vtb = (const float4*)(Vt + b * 14336);
  float q0[14], q1[14];
#pragma unroll
  for (int d = 0; d < 14; d++) {
    q0[d] = Qt[b * 14336 + d * 1024 + i0];
    q1[d] = Qt[b * 14336 + d * 1024 + i0 + 1];
  }

  float4 e10[4], e20[4], e11[4], e21[4];        // [t]: row0 h1, row0 h2, row1 h1, row1 h2
  float L10 = 0.f, L20 = 0.f, L11 = 0.f, L21 = 0.f;
  float acc0[14], acc1[14];
#pragma unroll
  for (int d = 0; d < 14; d++) { acc0[d] = 0.f; acc1[d] = 0.f; }
#pragma unroll
  for (int t = 0; t < 4; t++) {
    int g = t * 64 + lane;
    float4 kv[7];
#pragma unroll
    for (int d = 0; d < 7; d++) kv[d] = Ktb[d * 256 + g];
    float4 sa = {0,0,0,0}, sb = {0,0,0,0};
#pragma unroll
    for (int d = 0; d < 7; d++) { fma4(q0[d], kv[d], sa); fma4(q1[d], kv[d], sb); }
    e10[t] = exp4(sa); e11[t] = exp4(sb);
    L10 += e10[t].x + e10[t].y + e10[t].z + e10[t].w;
    L11 += e11[t].x + e11[t].y + e11[t].z + e11[t].w;
#pragma unroll
    for (int d = 0; d < 7; d++) kv[d] = Ktb[(d + 7) * 256 + g];
    sa = make_float4(0,0,0,0); sb = make_float4(0,0,0,0);
#pragma unroll
    for (int d = 0; d < 7; d++) { fma4(q0[d + 7], kv[d], sa); fma4(q1[d + 7], kv[d], sb); }
    e20[t] = exp4(sa); e21[t] = exp4(sb);
    L20 += e20[t].x + e20[t].y + e20[t].z + e20[t].w;
    L21 += e21[t].x + e21[t].y + e21[t].z + e21[t].w;
#pragma unroll
    for (int d = 0; d < 7; d++) {
      float4 vv = Vtb[d * 256 + g];
      acc0[d] += e10[t].x * vv.x + e10[t].y * vv.y + e10[t].z * vv.z + e10[t].w * vv.w;
      acc1[d] += e11[t].x * vv.x + e11[t].y * vv.y + e11[t].z * vv.z + e11[t].w * vv.w;
    }
#pragma unroll
    for (int d = 7; d < 14; d++) {
      float4 vv = Vtb[d * 256 + g];
      acc0[d] += e20[t].x * vv.x + e20[t].y * vv.y + e20[t].z * vv.z + e20[t].w * vv.w;
      acc1[d] += e21[t].x * vv.x + e21[t].y * vv.y + e21[t].z * vv.z + e21[t].w * vv.w;
    }
  }
  wave_sum2(L10, L20); wave_sum2(L11, L21);
  float i10 = 1.0f / L10, i20 = 1.0f / L20, i11 = 1.0f / L11, i21 = 1.0f / L21;

  float ent0 = 0.f, ent1 = 0.f;
#pragma unroll
  for (int t = 0; t < 4; t++) {
    float a;
    a = 0.5f * (e10[t].x * i10 + e20[t].x * i20); ent0 -= a * __logf(a + EPSF);
    a = 0.5f * (e10[t].y * i10 + e20[t].y * i20); ent0 -= a * __logf(a + EPSF);
    a = 0.5f * (e10[t].z * i10 + e20[t].z * i20); ent0 -= a * __logf(a + EPSF);
    a = 0.5f * (e10[t].w * i10 + e20[t].w * i20); ent0 -= a * __logf(a + EPSF);
    a = 0.5f * (e11[t].x * i11 + e21[t].x * i21); ent1 -= a * __logf(a + EPSF);
    a = 0.5f * (e11[t].y * i11 + e21[t].y * i21); ent1 -= a * __logf(a + EPSF);
    a = 0.5f * (e11[t].z * i11 + e21[t].z * i21); ent1 -= a * __logf(a + EPSF);
    a = 0.5f * (e11[t].w * i11 + e21[t].w * i21); ent1 -= a * __logf(a + EPSF);
  }
  wave_sum2(ent0, ent1);
#pragma unroll
  for (int d = 0; d < 14; d += 2) wave_sum2(acc0[d], acc0[d + 1]);
#pragma unroll
  for (int d = 0; d < 14; d += 2) wave_sum2(acc1[d], acc1[d + 1]);

  int row0 = b * 1024 + i0;
  if (lane == 0) {
    E1o[row0] = 0.5f * i10;  E2o[row0] = 0.5f * i20;
    E1o[row0 + 1] = 0.5f * i11; E2o[row0 + 1] = 0.5f * i21;
    cert_out[row0] = fmaxf(cert_in[row0], 1.0f / (1.0f + __expf(ent0 - MAXENT)));
    cert_out[row0 + 1] = fmaxf(cert_in[row0 + 1], 1.0f / (1.0f + __expf(ent1 - MAXENT)));
  }
  if (lane < 14) {
    int d = lane;
    float av0[14], av1[14];
#pragma unroll
    for (int k = 0; k < 14; k++) {
      av0[k] = acc0[k] * (k < 7 ? i10 : i20);
      av1[k] = acc1[k] * (k < 7 ? i11 : i21);
    }
    float s0 = boS[d], s1 = boS[d];
#pragma unroll
    for (int k = 0; k < 14; k++) {
      s0 = fmaf(av0[k], WoS[d * 14 + k], s0);
      s1 = fmaf(av1[k], WoS[d * 14 + k], s1);
    }
    out_[(size_t)row0 * 14 + d] = s0;
    out_[(size_t)(row0 + 1) * 14 + d] = s1;
  }
}

// ================= COOPERATIVE PERSISTENT SINK (fast path) =================
// One dispatch for: P0 build + iter1, 19 fused iterations, argmax (C20 folded),
// for both 32-batch groups. grid.sync() replaces 42 kernel boundaries.
// 256-thr blocks, 1024 virtual blocks; each wave owns 8 rows.
// v-accumulation: per-batch 4 KB column vector, 4-buffer rotation vW[0..3]
// (iteration t reads vW[(t-1)&3], atomicAdds vW[t&3], zeroes vW[(t+2)&3]).

__device__ __forceinline__ void p0_body(
    int vb, int b0,
    const float* __restrict__ Qt, const float* __restrict__ Kt,
    const float* __restrict__ E1, const float* __restrict__ E2,
    float* __restrict__ P0, float* __restrict__ R,
    float* __restrict__ vacc, float* __restrict__ vzero, float* vbuf) {
  int gb = vb >> 5, blk = vb & 31;
  int b = b0 + gb;
  int tid = threadIdx.x;
  __syncthreads();                               // vbuf reuse guard (virtual blocks)
  if (tid < 32) vzero[b * 1024 + blk * 32 + tid] = 0.f;
  int wave = tid >> 6, lane = tid & 63;
  int i0 = blk * 32 + wave * 8;
  const float4* Ktb = (const float4*)(Kt + b * 14336);
  float4* P0f4 = (float4*)P0;
  float u[8];
#pragma unroll
  for (int r = 0; r < 8; r++) u[r] = 0.f;
#pragma unroll 1
  for (int ch = 0; ch < 4; ch++) {               // 2 rows/chunk keeps VGPR < 128
    int ri = i0 + ch * 2;
    float q0[14], q1[14];
#pragma unroll
    for (int d = 0; d < 14; d++) {
      q0[d] = Qt[b * 14336 + d * 1024 + ri];
      q1[d] = Qt[b * 14336 + d * 1024 + ri + 1];
    }
    float e10 = E1[b * 1024 + ri], e20 = E2[b * 1024 + ri];
    float e11 = E1[b * 1024 + ri + 1], e21 = E2[b * 1024 + ri + 1];
#pragma unroll
    for (int t = 0; t < 4; t++) {
      int g = t * 64 + lane;
      float4 kv[7];
#pragma unroll
      for (int d = 0; d < 7; d++) kv[d] = Ktb[d * 256 + g];
      float4 sa = {0,0,0,0}, sb = {0,0,0,0};
#pragma unroll
      for (int d = 0; d < 7; d++) { fma4(q0[d], kv[d], sa); fma4(q1[d], kv[d], sb); }
#pragma unroll
      for (int d = 0; d < 7; d++) kv[d] = Ktb[(d + 7) * 256 + g];
      float4 s2a = {0,0,0,0}, s2b = {0,0,0,0};
#pragma unroll
      for (int d = 0; d < 7; d++) { fma4(q0[d + 7], kv[d], s2a); fma4(q1[d + 7], kv[d], s2b); }
      float4 pv;
      pv.x = p0e(sa.x, s2a.x, e10, e20);
      pv.y = p0e(sa.y, s2a.y, e10, e20);
      pv.z = p0e(sa.z, s2a.z, e10, e20);
      pv.w = p0e(sa.w, s2a.w, e10, e20);
      P0f4[(size_t)(gb * 1024 + ri) * 256 + g] = pv;
      u[ch * 2] += pv.x + pv.y + pv.z + pv.w;
      pv.x = p0e(sb.x, s2b.x, e11, e21);
      pv.y = p0e(sb.y, s2b.y, e11, e21);
      pv.z = p0e(sb.z, s2b.z, e11, e21);
      pv.w = p0e(sb.w, s2b.w, e11, e21);
      P0f4[(size_t)(gb * 1024 + ri + 1) * 256 + g] = pv;
      u[ch * 2 + 1] += pv.x + pv.y + pv.z + pv.w;
    }
  }
  wave_sum2(u[0], u[1]); wave_sum2(u[2], u[3]);
  wave_sum2(u[4], u[5]); wave_sum2(u[6], u[7]);
  float rv[8];
#pragma unroll
  for (int r = 0; r < 8; r++)
    rv[r] = fminf(1.0f / fmaf(1.0f, u[r], EPSF), 1e37f);
  if (lane == 0) {
#pragma unroll
    for (int r = 0; r < 8; r++) R[b * 1024 + i0 + r] = rv[r];
  }
  int l0 = lane, l1 = 64 + lane, l2 = 128 + lane, l3 = 192 + lane;
  float4 v0 = {0,0,0,0}, v1 = {0,0,0,0}, v2 = {0,0,0,0}, v3 = {0,0,0,0};
  const float4* basep = P0f4 + (size_t)(gb * 1024 + i0) * 256;
#pragma unroll 1
  for (int r = 0; r < 8; r++) {
    const float4* row = basep + r * 256;
    fma4(rv[r], row[l0], v0); fma4(rv[r], row[l1], v1);
    fma4(rv[r], row[l2], v2); fma4(rv[r], row[l3], v3);
  }
  float4* vb4 = (float4*)vbuf;
  vb4[wave * 256 + l0] = v0; vb4[wave * 256 + l1] = v1;
  vb4[wave * 256 + l2] = v2; vb4[wave * 256 + l3] = v3;
  __syncthreads();
  for (int col = tid; col < 1024; col += 256) {
    float v = vbuf[col] + vbuf[1024 + col] + vbuf[2048 + col] + vbuf[3072 + col];
    atomicAdd(&vacc[b * 1024 + col], v);
  }
}

__device__ __forceinline__ void sink_body(
    int vb, int b0,
    const float* __restrict__ P0, const float* __restrict__ Cin,
    float* __restrict__ Cout, float* __restrict__ R,
    const float* __restrict__ vin, float* __restrict__ vacc,
    float* __restrict__ vzero, float* vbuf) {
  int gb = vb >> 5, slice = vb & 31;
  int b = b0 + gb;
  int tid = threadIdx.x;
  __syncthreads();                               // vbuf reuse guard
  if (tid < 32) vzero[b * 1024 + slice * 32 + tid] = 0.f;
  int wave = tid >> 6, lane = tid & 63;
  int i0 = slice * 32 + wave * 8;
  int rbase = b * 1024 + i0;
  int l0 = lane, l1 = 64 + lane, l2 = 128 + lane, l3 = 192 + lane;
  const float4* base = (const float4*)P0 + (size_t)(gb * 1024 + i0) * 256;

  // first P0 row-pair issued ASAP (longest latency)
  float4 a0 = base[l0], a1 = base[l1], a2 = base[l2], a3 = base[l3];
  float4 b0f = base[256 + l0], b1f = base[256 + l1], b2f = base[256 + l2], b3f = base[256 + l3];

  // per-lane C' at this lane's 16 columns (deterministic, identical in all lanes)
  const float4* Cin4 = (const float4*)(Cin + b * 1024);
  const float4* vin4 = (const float4*)(vin + b * 1024);
  float4 c0 = cupd(Cin4[l0], vin4[l0]);
  float4 c1 = cupd(Cin4[l1], vin4[l1]);
  float4 c2 = cupd(Cin4[l2], vin4[l2]);
  float4 c3 = cupd(Cin4[l3], vin4[l3]);
  if (slice == 0 && wave == 0) {
    float4* Co4 = (float4*)(Cout + b * 1024);
    Co4[l0] = c0; Co4[l1] = c1; Co4[l2] = c2; Co4[l3] = c3;
  }
  float rreg[8];
#pragma unroll
  for (int r = 0; r < 8; r++) rreg[r] = R[rbase + r];

  float4 v0 = {0,0,0,0}, v1 = {0,0,0,0}, v2 = {0,0,0,0}, v3 = {0,0,0,0};
#pragma unroll
  for (int r = 0; r < 8; r += 2) {
    float4 na0, na1, na2, na3, nb0, nb1, nb2, nb3;
    if (r + 2 < 8) {
      const float4* nxt = base + (r + 2) * 256;
      na0 = nxt[l0]; na1 = nxt[l1]; na2 = nxt[l2]; na3 = nxt[l3];
      nb0 = nxt[256 + l0]; nb1 = nxt[256 + l1]; nb2 = nxt[256 + l2]; nb3 = nxt[256 + l3];
    }
    float ua = dot4(a3, c3, dot4(a2, c2, dot4(a1, c1, dot4(a0, c0, 0.f))));
    float ub = dot4(b3f, c3, dot4(b2f, c2, dot4(b1f, c1, dot4(b0f, c0, 0.f))));
    wave_sum2(ua, ub);
    float rva = rreg[r], rvb = rreg[r + 1];
    rva = fminf(rva / fmaf(rva, ua, EPSF), 1e37f);
    rvb = fminf(rvb / fmaf(rvb, ub, EPSF), 1e37f);
    if (lane == 0) { R[rbase + r] = rva; R[rbase + r + 1] = rvb; }
    fma4(rva, a0, v0); fma4(rva, a1, v1); fma4(rva, a2, v2); fma4(rva, a3, v3);
    fma4(rvb, b0f, v0); fma4(rvb, b1f, v1); fma4(rvb, b2f, v2); fma4(rvb, b3f, v3);
    if (r + 2 < 8) {
      a0 = na0; a1 = na1; a2 = na2; a3 = na3;
      b0f = nb0; b1f = nb1; b2f = nb2; b3f = nb3;
    }
  }
  float4* vb4 = (float4*)vbuf;
  vb4[wave * 256 + l0] = v0; vb4[wave * 256 + l1] = v1;
  vb4[wave * 256 + l2] = v2; vb4[wave * 256 + l3] = v3;
  __syncthreads();
  for (int col = tid; col < 1024; col += 256) {
    float v = vbuf[col] + vbuf[1024 + col] + vbuf[2048 + col] + vbuf[3072 + col];
    atomicAdd(&vacc[b * 1024 + col], v);
  }
}

__device__ __forceinline__ void argmax_body(
    int vb, int b0,
    const float* __restrict__ P0, const float* __restrict__ Cin,
    const float* __restrict__ vfin,
    const int* __restrict__ perm, float* __restrict__ perm_out) {
  int gb = vb >> 5, blk = vb & 31;
  int b = b0 + gb;
  int tid = threadIdx.x;
  int wave = tid >> 6, lane = tid & 63;
  int i0 = blk * 32 + wave * 8;
  const float4* Cin4 = (const float4*)(Cin + b * 1024);
  const float4* vin4 = (const float4*)(vfin + b * 1024);
  float4 cc[4];
#pragma unroll
  for (int t = 0; t < 4; t++) cc[t] = cupd(Cin4[t * 64 + lane], vin4[t * 64 + lane]);
#pragma unroll 1
  for (int r = 0; r < 8; r++) {
    int i = i0 + r;
    const float4* Prow = (const float4*)P0 + (size_t)(gb * 1024 + i) * 256;
    float best = -1.0f;
    int bj = 0;
#pragma unroll
    for (int t = 0; t < 4; t++) {
      int g = t * 64 + lane;
      float4 pv = Prow[g], cv = cc[t];
      float val;
      val = pv.x * cv.x; if (val > best) { best = val; bj = 4 * g + 0; }
      val = pv.y * cv.y; if (val > best) { best = val; bj = 4 * g + 1; }
      val = pv.z * cv.z; if (val > best) { best = val; bj = 4 * g + 2; }
      val = pv.w * cv.w; if (val > best) { best = val; bj = 4 * g + 3; }
    }
#pragma unroll
    for (int off = 32; off > 0; off >>= 1) {
      float ob = __shfl_xor(best, off);
      int oj = __shfl_xor(bj, off);
      if (ob > best || (ob == best && oj < bj)) { best = ob; bj = oj; }
    }
    if (lane == 0) perm_out[b * 1024 + i] = (float)perm[b * 1024 + bj];
  }
}

__global__ __launch_bounds__(256) void sink_coop(
    const float* __restrict__ Qt, const float* __restrict__ Kt,
    const float* __restrict__ E1, const float* __restrict__ E2,
    float* __restrict__ P0, float* __restrict__ R,
    float* __restrict__ CA, float* __restrict__ CB, float* __restrict__ vW,
    const int* __restrict__ perm, float* __restrict__ perm_out) {
  __shared__ float vbuf[4096];                   // 16 KB: 4 waves x 1024 cols
  cg::grid_group grid = cg::this_grid();
  for (int b0 = 0; b0 < 64; b0 += 32) {
    for (int vb = blockIdx.x; vb < 1024; vb += gridDim.x)
      p0_body(vb, b0, Qt, Kt, E1, E2, P0, R, vW + 65536, vW + 3 * 65536, vbuf);
    grid.sync();
    for (int it = 2; it <= 20; ++it) {
      const float* Cin = (it & 1) ? CB : CA;     // Cbuf[it&1]
      float* Cout = (it & 1) ? CA : CB;          // Cbuf[(it+1)&1]
      for (int vb = blockIdx.x; vb < 1024; vb += gridDim.x)
        sink_body(vb, b0, P0, Cin, Cout, R,
                  vW + (size_t)((it - 1) & 3) * 65536,
                  vW + (size_t)(it & 3) * 65536,
                  vW + (size_t)((it + 2) & 3) * 65536, vbuf);
      grid.sync();
    }
    // C19 in CB; argmax computes C20 = f(C19, v20 = vW[0]) per-lane
    for (int vb = blockIdx.x; vb < 1024; vb += gridDim.x)
      argmax_body(vb, b0, P0, CB, vW, perm, perm_out);
    grid.sync();                                 // P0 reused by next group
  }
}

// ================= FALLBACK multi-launch fast path (round-5 proven) =================

__global__ __launch_bounds__(512) void p0sink1_kernel(
    const float* __restrict__ Qt, const float* __restrict__ Kt,
    const float* __restrict__ E1, const float* __restrict__ E2,
    float* __restrict__ P0, float* __restrict__ R,
    float* __restrict__ vacc, float* __restrict__ vzero, int b0, int G) {
  __shared__ float4 Kl[3584];
  int gb = blockIdx.x >> 5, blk = blockIdx.x & 31;
  int b = b0 + gb;
  int tid = threadIdx.x;
  if (tid < 32) vzero[b * 1024 + blk * 32 + tid] = 0.f;
  const float4* Ktb = (const float4*)(Kt + b * 14336);
  for (int idx = tid; idx < 3584; idx += 512) Kl[idx] = Ktb[idx];
  __syncthreads();

  int wave = tid >> 6, lane = tid & 63;
  int i0 = blk * 32 + wave * 4;
  float q[4][14], e1r[4], e2r[4], u[4];
#pragma unroll
  for (int rr = 0; rr < 4; rr++) {
#pragma unroll
    for (int d = 0; d < 14; d++) q[rr][d] = Qt[b * 14336 + d * 1024 + i0 + rr];
    e1r[rr] = E1[b * 1024 + i0 + rr];
    e2r[rr] = E2[b * 1024 + i0 + rr];
    u[rr] = 0.f;
  }
  float4* P0f4 = (float4*)P0;
#pragma unroll
  for (int t = 0; t < 4; t++) {
    int g = t * 64 + lane;
    float4 kv[14];
#pragma unroll
    for (int d = 0; d < 14; d++) kv[d] = Kl[d * 256 + g];
#pragma unroll
    for (int rr = 0; rr < 4; rr++) {
      float4 s1 = {0,0,0,0}, s2 = {0,0,0,0};
#pragma unroll
      for (int d = 0; d < 7; d++)  fma4(q[rr][d], kv[d], s1);
#pragma unroll
      for (int d = 7; d < 14; d++) fma4(q[rr][d], kv[d], s2);
      float4 pv;
      pv.x = p0e(s1.x, s2.x, e1r[rr], e2r[rr]);
      pv.y = p0e(s1.y, s2.y, e1r[rr], e2r[rr]);
      pv.z = p0e(s1.z, s2.z, e1r[rr], e2r[rr]);
      pv.w = p0e(s1.w, s2.w, e1r[rr], e2r[rr]);
      P0f4[(size_t)(gb * 1024 + i0 + rr) * 256 + g] = pv;
      u[rr] += pv.x; u[rr] += pv.y; u[rr] += pv.z; u[rr] += pv.w;
    }
  }
  wave_sum2(u[0], u[1]); wave_sum2(u[2], u[3]);
  float rv[4];
#pragma unroll
  for (int rr = 0; rr < 4; rr++)
    rv[rr] = fminf(1.0f / fmaf(1.0f, u[rr], EPSF), 1e37f);
  if (lane == 0) {
#pragma unroll
    for (int rr = 0; rr < 4; rr++) R[b * 1024 + i0 + rr] = rv[rr];
  }
  int l0 = lane, l1 = 64 + lane, l2 = 128 + lane, l3 = 192 + lane;
  float4 v0 = {0,0,0,0}, v1 = {0,0,0,0}, v2 = {0,0,0,0}, v3 = {0,0,0,0};
  const float4* base = P0f4 + (size_t)(gb * 1024 + i0) * 256;
#pragma unroll
  for (int rr = 0; rr < 4; rr++) {
    const float4* row = base + rr * 256;
    fma4(rv[rr], row[l0], v0); fma4(rv[rr], row[l1], v1);
    fma4(rv[rr], row[l2], v2); fma4(rv[rr], row[l3], v3);
  }
  __syncthreads();
  float* vbuf = (float*)Kl;
  float4* vb4 = (float4*)vbuf;
  vb4[wave * 256 + l0] = v0; vb4[wave * 256 + l1] = v1;
  vb4[wave * 256 + l2] = v2; vb4[wave * 256 + l3] = v3;
  __syncthreads();
  for (int col = tid; col < 1024; col += 512) {
    float v = 0.f;
#pragma unroll
    for (int w = 0; w < 8; w++) v += vbuf[w * 1024 + col];
    atomicAdd(&vacc[b * 1024 + col], v);
  }
}

__global__ __launch_bounds__(512) void sink_fused(
    const float* __restrict__ P0, const float* __restrict__ Cin,
    float* __restrict__ Cout, float* __restrict__ R,
    const float* __restrict__ vin, float* __restrict__ vacc,
    float* __restrict__ vzero, int b0) {
  __shared__ float vbuf[8192];
  int tid = threadIdx.x;
  int gb = blockIdx.x >> 5, slice = blockIdx.x & 31;
  int b = b0 + gb;

  if (tid < 32) vzero[b * 1024 + slice * 32 + tid] = 0.f;

  int wave = tid >> 6, lane = tid & 63;
  int i0 = slice * 32 + wave * 4;
  int rbase = b * 1024 + i0;
  int l0 = lane, l1 = 64 + lane, l2 = 128 + lane, l3 = 192 + lane;
  const float4* base = (const float4*)P0 + (size_t)(gb * 1024 + i0) * 256;

  float4 a0 = base[l0], a1 = base[l1], a2 = base[l2], a3 = base[l3];
  float4 b0f = base[256 + l0], b1f = base[256 + l1], b2f = base[256 + l2], b3f = base[256 + l3];

  const float4* Cin4 = (const float4*)(Cin + b * 1024);
  const float4* vin4 = (const float4*)(vin + b * 1024);
  float4 c0 = cupd(Cin4[l0], vin4[l0]);
  float4 c1 = cupd(Cin4[l1], vin4[l1]);
  float4 c2 = cupd(Cin4[l2], vin4[l2]);
  float4 c3 = cupd(Cin4[l3], vin4[l3]);
  if (slice == 0 && wave == 0) {
    float4* Co4 = (float4*)(Cout + b * 1024);
    Co4[l0] = c0; Co4[l1] = c1; Co4[l2] = c2; Co4[l3] = c3;
  }

  float rreg[4];
#pragma unroll
  for (int r = 0; r < 4; r++) rreg[r] = R[rbase + r];

  float4 v0 = {0,0,0,0}, v1 = {0,0,0,0}, v2 = {0,0,0,0}, v3 = {0,0,0,0};
#pragma unroll
  for (int r = 0; r < 4; r += 2) {
    float4 na0, na1, na2, na3, nb0, nb1, nb2, nb3;
    if (r + 2 < 4) {
      const float4* nxt = base + (r + 2) * 256;
      na0 = nxt[l0]; na1 = nxt[l1]; na2 = nxt[l2]; na3 = nxt[l3];
      nb0 = nxt[256 + l0]; nb1 = nxt[256 + l1]; nb2 = nxt[256 + l2]; nb3 = nxt[256 + l3];
    }
    float ua = dot4(a3, c3, dot4(a2, c2, dot4(a1, c1, dot4(a0, c0, 0.f))));
    float ub = dot4(b3f, c3, dot4(b2f, c2, dot4(b1f, c1, dot4(b0f, c0, 0.f))));
    wave_sum2(ua, ub);
    float rva = rreg[r], rvb = rreg[r + 1];
    rva = fminf(rva / fmaf(rva, ua, EPSF), 1e37f);
    rvb = fminf(rvb / fmaf(rvb, ub, EPSF), 1e37f);
    if (lane == 0) { R[rbase + r] = rva; R[rbase + r + 1] = rvb; }
    fma4(rva, a0, v0); fma4(rva, a1, v1); fma4(rva, a2, v2); fma4(rva, a3, v3);
    fma4(rvb, b0f, v0); fma4(rvb, b1f, v1); fma4(rvb, b2f, v2); fma4(rvb, b3f, v3);
    if (r + 2 < 4) {
      a0 = na0; a1 = na1; a2 = na2; a3 = na3;
      b0f = nb0; b1f = nb1; b2f = nb2; b3f = nb3;
    }
  }
  float4* vb4 = (float4*)vbuf;
  vb4[wave * 256 + l0] = v0; vb4[wave * 256 + l1] = v1;
  vb4[wave * 256 + l2] = v2; vb4[wave * 256 + l3] = v3;
  __syncthreads();
  for (int col = tid; col < 1024; col += 512) {
    float v = 0.f;
#pragma unroll
    for (int w = 0; w < 8; w++) v += vbuf[w * 1024 + col];
    atomicAdd(&vacc[b * 1024 + col], v);
  }
}

__global__ __launch_bounds__(512) void argmaxP_kernel(
    const float* __restrict__ P0, const float* __restrict__ Cin,
    const float* __restrict__ vfin,
    const int* __restrict__ perm, float* __restrict__ perm_out, int b0) {
  int gb = blockIdx.x >> 7, rg = blockIdx.x & 127;
  int b = b0 + gb;
  int tid = threadIdx.x;
  int wave = tid >> 6, lane = tid & 63;
  int i = rg * 8 + wave;
  const float4* Prow = (const float4*)P0 + (size_t)(gb * 1024 + i) * 256;
  const float4* Cin4 = (const float4*)(Cin + b * 1024);
  const float4* vin4 = (const float4*)(vfin + b * 1024);
  float4 cc[4];
#pragma unroll
  for (int t = 0; t < 4; t++) cc[t] = cupd(Cin4[t * 64 + lane], vin4[t * 64 + lane]);

  float best = -1.0f;
  int bj = 0;
#pragma unroll
  for (int t = 0; t < 4; t++) {
    int g = t * 64 + lane;
    float4 pv = Prow[g], cv = cc[t];
    float val;
    val = pv.x * cv.x; if (val > best) { best = val; bj = 4 * g + 0; }
    val = pv.y * cv.y; if (val > best) { best = val; bj = 4 * g + 1; }
    val = pv.z * cv.z; if (val > best) { best = val; bj = 4 * g + 2; }
    val = pv.w * cv.w; if (val > best) { best = val; bj = 4 * g + 3; }
  }
#pragma unroll
  for (int off = 32; off > 0; off >>= 1) {
    float ob = __shfl_xor(best, off);
    int oj = __shfl_xor(bj, off);
    if (ob > best || (ob == best && oj < bj)) { best = ob; bj = oj; }
  }
  if (lane == 0) perm_out[b * 1024 + i] = (float)perm[b * 1024 + bj];
}

// ================= FALLBACK PATH (recompute, no P0 workspace) =================

__global__ __launch_bounds__(512) void sinkA_kernel(
    const float* __restrict__ Qt, const float* __restrict__ Kt,
    const float* __restrict__ E1, const float* __restrict__ E2,
    const float* __restrict__ C, float* __restrict__ R) {
  __shared__ float4 Kl[3584];
  int b = blockIdx.x >> 5, blk = blockIdx.x & 31;
  int tid = threadIdx.x;
  const float4* Ktb = (const float4*)(Kt + b * 14336);
  for (int idx = tid; idx < 3584; idx += 512) Kl[idx] = Ktb[idx];
  __syncthreads();
  int wave = tid >> 6, lane = tid & 63;
  int i0 = blk * 32 + wave * 4;
  float q[4][14], e1r[4], e2r[4], u[4];
#pragma unroll
  for (int rr = 0; rr < 4; rr++) {
#pragma unroll
    for (int d = 0; d < 14; d++) q[rr][d] = Qt[b * 14336 + d * 1024 + i0 + rr];
    e1r[rr] = E1[b * 1024 + i0 + rr];
    e2r[rr] = E2[b * 1024 + i0 + rr];
    u[rr] = 0.f;
  }
  const float4* Cb = (const float4*)(C + b * 1024);
#pragma unroll
  for (int t = 0; t < 4; t++) {
    int g = t * 64 + lane;
    float4 kv[14];
#pragma unroll
    for (int d = 0; d < 14; d++) kv[d] = Kl[d * 256 + g];
    float4 cv = Cb[g];
#pragma unroll
    for (int rr = 0; rr < 4; rr++) {
      float4 s1 = {0,0,0,0}, s2 = {0,0,0,0};
#pragma unroll
      for (int d = 0; d < 7; d++)  fma4(q[rr][d], kv[d], s1);
#pragma unroll
      for (int d = 7; d < 14; d++) fma4(q[rr][d], kv[d], s2);
      u[rr] += p0e(s1.x, s2.x, e1r[rr], e2r[rr]) * cv.x;
      u[rr] += p0e(s1.y, s2.y, e1r[rr], e2r[rr]) * cv.y;
      u[rr] += p0e(s1.z, s2.z, e1r[rr], e2r[rr]) * cv.z;
      u[rr] += p0e(s1.w, s2.w, e1r[rr], e2r[rr]) * cv.w;
    }
  }
#pragma unroll
  for (int rr = 0; rr < 4; rr++) u[rr] = wave_sum(u[rr]);
  if (lane == 0) {
#pragma unroll
    for (int rr = 0; rr < 4; rr++) {
      int o = b * 1024 + i0 + rr;
      float rv = R[o];
      R[o] = fminf(rv / fmaf(rv, u[rr], EPSF), 1e37f);
    }
  }
}

__global__ __launch_bounds__(512) void sinkB_kernel(
    const float* __restrict__ Qt, const float* __restrict__ Kt,
    const float* __restrict__ E1, const float* __restrict__ E2,
    const float* __restrict__ R, float* __restrict__ C) {
  __shared__ float4 Ql[3584];
  int b = blockIdx.x >> 5, blk = blockIdx.x & 31;
  int tid = threadIdx.x;
  const float4* Qtb = (const float4*)(Qt + b * 14336);
  for (int idx = tid; idx < 3584; idx += 512) Ql[idx] = Qtb[idx];
  __syncthreads();
  int wave = tid >> 6, lane = tid & 63;
  int j0 = blk * 32 + wave * 4;
  float kk[4][14], v[4];
#pragma unroll
  for (int rr = 0; rr < 4; rr++) {
#pragma unroll
    for (int d = 0; d < 14; d++) kk[rr][d] = Kt[b * 14336 + d * 1024 + j0 + rr];
    v[rr] = 0.f;
  }
  const float4* E1b = (const float4*)(E1 + b * 1024);
  const float4* E2b = (const float4*)(E2 + b * 1024);
  const float4* Rb  = (const float4*)(R + b * 1024);
#pragma unroll
  for (int t = 0; t < 4; t++) {
    int g = t * 64 + lane;
    float4 qv[14];
#pragma unroll
    for (int d = 0; d < 14; d++) qv[d] = Ql[d * 256 + g];
    float4 e1v = E1b[g], e2v = E2b[g], rv = Rb[g];
#pragma unroll
    for (int rr = 0; rr < 4; rr++) {
      float4 s1 = {0,0,0,0}, s2 = {0,0,0,0};
#pragma unroll
      for (int d = 0; d < 7; d++)  fma4(kk[rr][d], qv[d], s1);
#pragma unroll
      for (int d = 7; d < 14; d++) fma4(kk[rr][d], qv[d], s2);
      v[rr] += p0e(s1.x, s2.x, e1v.x, e2v.x) * rv.x;
      v[rr] += p0e(s1.y, s2.y, e1v.y, e2v.y) * rv.y;
      v[rr] += p0e(s1.z, s2.z, e1v.z, e2v.z) * rv.z;
      v[rr] += p0e(s1.w, s2.w, e1v.w, e2v.w) * rv.w;
    }
  }
#pragma unroll
  for (int rr = 0; rr < 4; rr++) v[rr] = wave_sum(v[rr]);
  if (lane == 0) {
#pragma unroll
    for (int rr = 0; rr < 4; rr++) {
      int o = b * 1024 + j0 + rr;
      float cv = C[o];
      C[o] = fminf(cv / fmaf(cv, v[rr], EPSF), 1e37f);
    }
  }
}

__global__ __launch_bounds__(512) void argmax_kernel(
    const float* __restrict__ Qt, const float* __restrict__ Kt,
    const float* __restrict__ E1, const float* __restrict__ E2,
    const float* __restrict__ C, const int* __restrict__ perm,
    float* __restrict__ perm_out) {
  __shared__ float4 Kl[3584];
  int b = blockIdx.x >> 7, rg = blockIdx.x & 127;
  int tid = threadIdx.x;
  const float4* Ktb = (const float4*)(Kt + b * 14336);
  for (int idx = tid; idx < 3584; idx += 512) Kl[idx] = Ktb[idx];
  __syncthreads();
  int wave = tid >> 6, lane = tid & 63;
  int i = rg * 8 + wave;
  int row = b * 1024 + i;
  float q[14];
#pragma unroll
  for (int d = 0; d < 14; d++) q[d] = Qt[b * 14336 + d * 1024 + i];
  float e1r = E1[row], e2r = E2[row];
  const float4* Cb = (const float4*)(C + b * 1024);
  float best = -1.0f;
  int bj = 0;
#pragma unroll
  for (int t = 0; t < 4; t++) {
    int g = t * 64 + lane;
    float4 kv[14];
#pragma unroll
    for (int d = 0; d < 14; d++) kv[d] = Kl[d * 256 + g];
    float4 cv = Cb[g];
    float4 s1 = {0,0,0,0}, s2 = {0,0,0,0};
#pragma unroll
    for (int d = 0; d < 7; d++)  fma4(q[d], kv[d], s1);
#pragma unroll
    for (int d = 7; d < 14; d++) fma4(q[d], kv[d], s2);
    float val;
    val = p0e(s1.x, s2.x, e1r, e2r) * cv.x; if (val > best) { best = val; bj = 4 * g + 0; }
    val = p0e(s1.y, s2.y, e1r, e2r) * cv.y; if (val > best) { best = val; bj = 4 * g + 1; }
    val = p0e(s1.z, s2.z, e1r, e2r) * cv.z; if (val > best) { best = val; bj = 4 * g + 2; }
    val = p0e(s1.w, s2.w, e1r, e2r) * cv.w; if (val > best) { best = val; bj = 4 * g + 3; }
  }
#pragma unroll
  for (int off = 32; off > 0; off >>= 1) {
    float ob = __shfl_xor(best, off);
    int oj = __shfl_xor(bj, off);
    if (ob > best || (ob == best && oj < bj)) { best = ob; bj = oj; }
  }
  if (lane == 0) perm_out[row] = (float)perm[b * 1024 + bj];
}

// ---------------- launch ----------------
extern "C" void kernel_launch(void* const* d_in, const int* in_sizes, int n_in,
                              void* d_out, int out_size, void* d_ws, size_t ws_size,
                              hipStream_t stream) {
  const float* x    = (const float*)d_in[0];
  const float* cert = (const float*)d_in[1];
  const int*   perm = (const int*)d_in[2];
  const float* Wq = (const float*)d_in[3];
  const float* bq = (const float*)d_in[4];
  const float* Wk = (const float*)d_in[5];
  const float* bk = (const float*)d_in[6];
  const float* Wv = (const float*)d_in[7];
  const float* bv = (const float*)d_in[8];
  const float* Wo = (const float*)d_in[9];
  const float* bo = (const float*)d_in[10];

  float* out      = (float*)d_out;            // 917504
  float* cert_out = out + 917504;             // 65536
  float* perm_out = out + 983040;             // 65536

  float* ws = (float*)d_ws;
  float* Qt = ws;                    // 917504
  float* Kt = Qt + 917504;           // 917504
  float* Vt = Kt + 917504;           // 917504
  float* E1 = Vt + 917504;           // 65536
  float* E2 = E1 + 65536;            // 65536
  float* R  = E2 + 65536;            // 65536
  float* CA = R + 65536;             // 65536  (C ping)
  float* CB = CA + 65536;            // 65536  (C pong)
  float* vW = CB + 65536;            // 4 x 65536 v-rotation buffers
  float* P0 = vW + 262144;           // G * 1048576

  // ws is ~256 MB: G=32 (P0 = 128 MiB) is the ceiling (round-5 evidence).
  size_t base_f = 3342336u;
  size_t avail_f = (ws_size / 4 > base_f) ? (ws_size / 4 - base_f) : 0;
  size_t perG = 1048576u;
  int G = 0;
  if (avail_f >= 32 * perG) G = 32;
  else if (avail_f >= 16 * perG) G = 16;

  // one-time cooperative-launch capability + occupancy probe
  static int coopGrid = -2;
  if (coopGrid == -2) {
    int dev = 0;
    hipGetDevice(&dev);
    int supported = 0;
    hipDeviceGetAttribute(&supported, hipDeviceAttributeCooperativeLaunch, dev);
    int nCU = 0;
    hipDeviceGetAttribute(&nCU, hipDeviceAttributeMultiprocessorCount, dev);
    int maxB = 0;
    hipError_t oe = hipOccupancyMaxActiveBlocksPerMultiprocessor(
        &maxB, reinterpret_cast<const void*>(&sink_coop), 256, 0);
    int cap = (oe == hipSuccess) ? maxB * nCU : 0;
    coopGrid = (supported && cap >= 256) ? (cap < 1024 ? cap : 1024) : 0;
  }

  float* Cbuf[2] = {CA, CB};

  qkv_kernel<<<256, 256, 0, stream>>>(x, Wq, bq, Wk, bk, Wv, bv, Qt, Kt, Vt, R, CA, CB, vW);
  attn_kernel<<<8192, 256, 0, stream>>>(Qt, Kt, Vt, cert, Wo, bo, E1, E2, out, cert_out);

  bool done = false;
  if (G >= 32 && coopGrid > 0) {
    void* args[] = {
      (void*)&Qt, (void*)&Kt, (void*)&E1, (void*)&E2, (void*)&P0, (void*)&R,
      (void*)&CA, (void*)&CB, (void*)&vW, (void*)&perm, (void*)&perm_out
    };
    hipError_t e = hipLaunchCooperativeKernel(
        reinterpret_cast<const void*>(&sink_coop),
        dim3(coopGrid), dim3(256), args, 0, stream);
    if (e == hipSuccess) done = true;
    else coopGrid = 0;                          // disable for future calls
  }

  if (!done && G >= 16) {
    for (int b0 = 0; b0 < 64; b0 += G) {
      p0sink1_kernel<<<G * 32, 512, 0, stream>>>(Qt, Kt, E1, E2, P0, R,
          vW + 65536, vW + 3 * 65536, b0, G);
      for (int it = 2; it <= 20; it++) {
        sink_fused<<<G * 32, 512, 0, stream>>>(P0, Cbuf[it & 1], Cbuf[(it + 1) & 1], R,
            vW + (size_t)((it - 1) & 3) * 65536,
            vW + (size_t)(it & 3) * 65536,
            vW + (size_t)((it + 2) & 3) * 65536, b0);
      }
      argmaxP_kernel<<<G * 128, 512, 0, stream>>>(P0, Cbuf[1], vW, perm, perm_out, b0);
    }
    done = true;
  }

  if (!done) {
    for (int it = 0; it < 20; it++) {
      sinkA_kernel<<<2048, 512, 0, stream>>>(Qt, Kt, E1, E2, CA, R);
      sinkB_kernel<<<2048, 512, 0, stream>>>(Qt, Kt, E1, E2, R, CA);
    }
    argmax_kernel<<<8192, 512, 0, stream>>>(Qt, Kt, E1, E2, CA, perm, perm_out);
  }
}